// Round 9
// baseline (751.837 us; speedup 1.0000x reference)
//
#include <hip/hip_runtime.h>
#include <math.h>

#define NB 4
#define T 65536
#define TIN 8192
#define LL 256
#define KCL 6144   // per-layer kernel channels = 32*64*3

__device__ __forceinline__ float lrelu_f(float v) { return v >= 0.f ? v : 0.2f * v; }

// ---------------- phase1: convt (264 blocks) + trunk (32 blocks) merged (R0, measured 112us) ----------------
union Phase1LDS {
    struct { float xs[32][264]; float wm[64][128]; } cvt;            // 65.8 KB
    struct { float hs[64][56]; float xsp[20][56]; float wt[192][68]; } trk; // 71.0 KB
};

__global__ void __launch_bounds__(512) phase1(
    const float* __restrict__ x, const float* __restrict__ cw,
    const float* __restrict__ cbias, float* __restrict__ hout,
    const float* __restrict__ spec,
    const float* __restrict__ kp_in_w, const float* __restrict__ kp_in_b,
    const float* __restrict__ rb_w1, const float* __restrict__ rb_b1,
    const float* __restrict__ rb_w2, const float* __restrict__ rb_b2,
    float* __restrict__ kp_h) {
    __shared__ Phase1LDS u;
    const int bid = blockIdx.x;
    const int tid = threadIdx.x;
    const int lane = tid & 63, wv = tid >> 6;

    if (bid < 264) {
        // ================= convt role =================
        const int bx = bid % 33;
        const int rr = bid / 33;
        const int mtp = rr & 1;
        const int b = rr >> 1;
        const int s0base = bx * 256;
        float (*xs)[264] = u.cvt.xs;
        float (*wm)[128] = u.cvt.wm;

        const float* xb = x + (size_t)b * 32 * TIN;
        for (int idx = tid; idx < 32 * 64; idx += 512) {
            int c = idx >> 6, q = idx & 63;
            int p = s0base + q * 4;
            float4 v = (p + 3 < TIN) ? *(const float4*)(xb + c * TIN + p)
                                     : make_float4(0.f, 0.f, 0.f, 0.f);
            *(float4*)&xs[c][4 + 4 * q] = v;
        }
        if (tid < 32) {
            int p = s0base - 1;
            xs[tid][3] = (p >= 0) ? xb[tid * TIN + p] : 0.f;
        }
        for (int idx = tid; idx < 8192; idx += 512) {
            int i = idx >> 7, mm = idx & 127;
            int oo = mtp * 16 + (mm >> 3), k0 = mm & 7;
            wm[i][mm] = (i < 32) ? cw[i * 512 + oo * 16 + k0]
                                 : cw[(i - 32) * 512 + oo * 16 + k0 + 8];
        }
        __syncthreads();

        float acc[2][8][4];   // [ol][k0][si]
#pragma unroll
        for (int ol = 0; ol < 2; ++ol) {
            float bo = cbias[mtp * 16 + wv * 2 + ol];
#pragma unroll
            for (int k0 = 0; k0 < 8; ++k0)
#pragma unroll
                for (int si = 0; si < 4; ++si) acc[ol][k0][si] = bo;
        }

        for (int c = 0; c < 32; ++c) {
            float xm1[4], x0[4];
#pragma unroll
            for (int si = 0; si < 4; ++si) {
                xm1[si] = xs[c][lane + si * 64 + 3];
                x0[si]  = xs[c][lane + si * 64 + 4];
            }
            float w0[16], w1[16];
#pragma unroll
            for (int q = 0; q < 4; ++q) {
                *(float4*)&w0[q * 4] = *(const float4*)&wm[c][wv * 16 + q * 4];
                *(float4*)&w1[q * 4] = *(const float4*)&wm[32 + c][wv * 16 + q * 4];
            }
#pragma unroll
            for (int ol = 0; ol < 2; ++ol)
#pragma unroll
                for (int k0 = 0; k0 < 8; ++k0)
#pragma unroll
                    for (int si = 0; si < 4; ++si)
                        acc[ol][k0][si] += x0[si] * w0[ol * 8 + k0] + xm1[si] * w1[ol * 8 + k0];
        }

#pragma unroll
        for (int ol = 0; ol < 2; ++ol) {
            float* ob = hout + ((size_t)b * 32 + mtp * 16 + wv * 2 + ol) * T;
#pragma unroll
            for (int si = 0; si < 4; ++si) {
                int tb = (s0base + lane + si * 64) * 8 - 4;
                if (tb >= 0 && tb < T)
                    *(float4*)(ob + tb) = make_float4(acc[ol][0][si], acc[ol][1][si],
                                                      acc[ol][2][si], acc[ol][3][si]);
                if (tb + 4 >= 0 && tb + 4 < T)
                    *(float4*)(ob + tb + 4) = make_float4(acc[ol][4][si], acc[ol][5][si],
                                                          acc[ol][6][si], acc[ol][7][si]);
            }
        }
        return;
    }

    // ================= trunk role =================
    const int tb = bid - 264;
    const int lq = tb & 7, b = tb >> 3;
    const int j = lane;
    const int oc0 = wv * 8;
    const int l0 = lq * 32;
    const int labs = l0 - 9 + j;
    const bool lvalid = (labs >= 0 && labs < 256);

    float (*hs)[56] = u.trk.hs;
    float (*xsp)[56] = u.trk.xsp;
    float (*wt)[68] = u.trk.wt;

    float pw[24];
    float px[3];

    auto pf_kpin = [&](int cc) {
#pragma unroll
        for (int t = 0; t < 13; ++t) {
            int idx = t * 512 + tid;
            pw[t] = 0.f;
            if (idx < 6400) pw[t] = kp_in_w[(size_t)(idx / 100) * 500 + cc * 100 + (idx % 100)];
        }
    };
    auto wr_kpin = [&]() {
#pragma unroll
        for (int t = 0; t < 13; ++t) {
            int idx = t * 512 + tid;
            if (idx < 6400) wt[idx % 100][idx / 100] = pw[t];
        }
    };
    auto pf_xsp = [&](int cc) {
#pragma unroll
        for (int t = 0; t < 3; ++t) {
            int idx = t * 512 + tid;
            px[t] = 0.f;
            if (idx < 1120) {
                int c = idx / 56, jj = idx - c * 56;
                int l = l0 - 9 + jj;
                if (l >= 0 && l < 256)
                    px[t] = spec[((size_t)b * 100 + cc * 20 + c) * LL + l];
            }
        }
    };
    auto wr_xsp = [&]() {
#pragma unroll
        for (int t = 0; t < 3; ++t) {
            int idx = t * 512 + tid;
            if (idx < 1120) xsp[idx / 56][idx % 56] = px[t];
        }
    };
    auto pf_w192 = [&](const float* src) {
#pragma unroll
        for (int t = 0; t < 24; ++t) pw[t] = src[t * 512 + tid];
    };
    auto wr_w192 = [&]() {
#pragma unroll
        for (int t = 0; t < 24; ++t) {
            int idx = t * 512 + tid;
            wt[idx % 192][idx / 192] = pw[t];
        }
    };
    auto conv64 = [&](int jlo, int jhi, const float* bptr, float* a) {
#pragma unroll
        for (int oi = 0; oi < 8; ++oi) a[oi] = bptr[oc0 + oi];
        if (j >= jlo && j < jhi) {
            for (int c = 0; c < 64; ++c) {
                float x0 = hs[c][j - 1], x1 = hs[c][j], x2 = hs[c][j + 1];
#pragma unroll
                for (int k = 0; k < 3; ++k) {
                    float xk = (k == 0) ? x0 : (k == 1) ? x1 : x2;
                    float w8[8];
                    *(float4*)&w8[0] = *(const float4*)&wt[c * 3 + k][oc0];
                    *(float4*)&w8[4] = *(const float4*)&wt[c * 3 + k][oc0 + 4];
#pragma unroll
                    for (int oi = 0; oi < 8; ++oi) a[oi] += xk * w8[oi];
                }
            }
        }
    };

    // ---- kp_in: 5 cc pages ----
    pf_kpin(0); pf_xsp(0);
    wr_kpin(); wr_xsp();
    __syncthreads();

    float acc[8];
#pragma unroll
    for (int oi = 0; oi < 8; ++oi) acc[oi] = kp_in_b[oc0 + oi];

    for (int cc = 0; cc < 5; ++cc) {
        if (cc < 4) { pf_kpin(cc + 1); pf_xsp(cc + 1); }
        else        { pf_w192(rb_w1); }
        if (j >= 2 && j < 48) {
            for (int c = 0; c < 20; ++c) {
                float x5[5];
#pragma unroll
                for (int u2 = 0; u2 < 5; ++u2) x5[u2] = xsp[c][j - 2 + u2];
#pragma unroll
                for (int k = 0; k < 5; ++k) {
                    float w8[8];
                    *(float4*)&w8[0] = *(const float4*)&wt[c * 5 + k][oc0];
                    *(float4*)&w8[4] = *(const float4*)&wt[c * 5 + k][oc0 + 4];
#pragma unroll
                    for (int oi = 0; oi < 8; ++oi) acc[oi] += x5[k] * w8[oi];
                }
            }
        }
        if (cc == 4 && j >= 2 && j < 48) {
#pragma unroll
            for (int oi = 0; oi < 8; ++oi) hs[oc0 + oi][j] = lvalid ? acc[oi] : 0.f;
        }
        __syncthreads();
        if (cc < 4) { wr_kpin(); wr_xsp(); }
        else        { wr_w192(); }
        __syncthreads();
    }

    // ---- 3 residual blocks ----
    for (int i = 0; i < 3; ++i) {
        const int jlo1 = 3 + 2 * i, jhi1 = 47 - 2 * i;
        const int jlo2 = jlo1 + 1, jhi2 = jhi1 - 1;
        float r[8];
        if (j >= jlo2 && j < jhi2) {
#pragma unroll
            for (int oi = 0; oi < 8; ++oi) r[oi] = hs[oc0 + oi][j];
        }
        // conv1
        pf_w192(rb_w2 + (size_t)i * 12288);
        float a1[8];
        conv64(jlo1, jhi1, rb_b1 + i * 64, a1);
        __syncthreads();
        if (j >= jlo1 && j < jhi1) {
#pragma unroll
            for (int oi = 0; oi < 8; ++oi) hs[oc0 + oi][j] = lvalid ? lrelu_f(a1[oi]) : 0.f;
        }
        wr_w192();
        __syncthreads();
        // conv2
        if (i < 2) pf_w192(rb_w1 + (size_t)(i + 1) * 12288);
        float a2[8];
        conv64(jlo2, jhi2, rb_b2 + i * 64, a2);
        __syncthreads();
        if (j >= jlo2 && j < jhi2) {
#pragma unroll
            for (int oi = 0; oi < 8; ++oi) hs[oc0 + oi][j] = lvalid ? (lrelu_f(a2[oi]) + r[oi]) : 0.f;
        }
        if (i < 2) wr_w192();
        __syncthreads();
    }

    // ---- write kp_h (central 32 cols) ----
    for (int idx = tid; idx < 64 * 32; idx += 512) {
        int c = idx >> 5, jj = idx & 31;
        kp_h[((size_t)b * 64 + c) * LL + l0 + jj] = hs[c][9 + jj];
    }
}

// ---------------- kern head core: 512 threads, 8 waves x 4 oc; col = 4*lane+q (b128 x reads) ----------------
__device__ __forceinline__ void khead_core(
    int bx, int b, int tid,
    const float* __restrict__ kp_h, const float* __restrict__ kw,
    const float* __restrict__ kb, const float* __restrict__ bias_w,
    const float* __restrict__ bias_b, float* __restrict__ kh,
    float* __restrict__ bh, int layer,
    float (*xs)[264], float (*ws)[36]) {
    const bool isbias = (bx >= 192);
    const int lane = tid & 63, wv = tid >> 6;   // wv 0..7
    int g = 0, oc0 = 0, ci = 0, kk = 0, ocb0 = 0;
    const float* wsrc;
    size_t wrow0;
    int wstride;
    if (!isbias) {
        g = bx >> 1; oc0 = (bx & 1) * 32;
        ci = g / 3; kk = g - ci * 3;
        wsrc = kw + (size_t)layer * KCL * 192;
        wrow0 = (size_t)((ci * 64 + oc0) * 3 + kk) * 192;
        wstride = 576;
    } else {
        ocb0 = (bx - 192) * 32;
        wsrc = bias_w;
        wrow0 = (size_t)ocb0 * 192;
        wstride = 192;
    }
    const int oc4w = wv * 4;

    float acc[4][4];   // [oi][q], col = 4*lane+q
#pragma unroll
    for (int oi = 0; oi < 4; ++oi) {
        float bv = isbias ? bias_b[ocb0 + oc4w + oi]
                          : kb[layer * KCL + (ci * 64 + oc0 + oc4w + oi) * 3 + kk];
#pragma unroll
        for (int q = 0; q < 4; ++q) acc[oi][q] = bv;
    }

    for (int half = 0; half < 2; ++half) {
        const int hc0 = half * 32;
        __syncthreads();
        for (int idx = tid; idx < 32 * 64; idx += 512) {
            int c = idx >> 6, q = idx & 63;
            *(float4*)&xs[c][4 + 4 * q] =
                *(const float4*)(kp_h + ((size_t)b * 64 + hc0 + c) * LL + 4 * q);
        }
        if (tid < 32) { xs[tid][3] = 0.f; xs[tid][260] = 0.f; }
        for (int idx = tid; idx < 3072; idx += 512) {
            int ocl = idx / 96, jj = idx - ocl * 96;
            ws[jj][ocl] = wsrc[wrow0 + (size_t)ocl * wstride + hc0 * 3 + jj];
        }
        __syncthreads();
        for (int c = 0; c < 32; ++c) {
            float4 xa = *(const float4*)&xs[c][4 * lane];        // only .w used
            float4 xm = *(const float4*)&xs[c][4 + 4 * lane];
            float4 xb = *(const float4*)&xs[c][8 + 4 * lane];    // only .x used
            float xx[6] = {xa.w, xm.x, xm.y, xm.z, xm.w, xb.x};
#pragma unroll
            for (int t = 0; t < 3; ++t) {
                float4 w4 = *(const float4*)&ws[c * 3 + t][oc4w];
#pragma unroll
                for (int q = 0; q < 4; ++q) {
                    acc[0][q] += w4.x * xx[q + t];
                    acc[1][q] += w4.y * xx[q + t];
                    acc[2][q] += w4.z * xx[q + t];
                    acc[3][q] += w4.w * xx[q + t];
                }
            }
        }
    }

    if (!isbias) {
#pragma unroll
        for (int q = 0; q < 4; ++q) {
            int l = 4 * lane + q;
            float* op = kh + ((size_t)b * LL + l) * KCL + g * 64 + oc0 + oc4w;
            *(float4*)op = make_float4(acc[0][q], acc[1][q], acc[2][q], acc[3][q]);
        }
    } else {
#pragma unroll
        for (int oi = 0; oi < 4; ++oi) {
            float* op = bh + ((size_t)b * 256 + ocb0 + oc4w + oi) * LL + 4 * lane;
            *(float4*)op = make_float4(acc[oi][0], acc[oi][1], acc[oi][2], acc[oi][3]);
        }
    }
}

__global__ void __launch_bounds__(512, 2) kern_head512(
    const float* __restrict__ kp_h, const float* __restrict__ kw,
    const float* __restrict__ kb, const float* __restrict__ bias_w,
    const float* __restrict__ bias_b, float* __restrict__ kh,
    float* __restrict__ bh, int layer) {
    __shared__ float xs[32][264];
    __shared__ float ws[96][36];
    khead_core(blockIdx.x, blockIdx.y, threadIdx.x, kp_h, kw, kb, bias_w, bias_b,
               kh, bh, layer, xs, ws);
}

// ---------------- layer_fused core: Phases A/B/C = R0; Phase D/E = R7 form ----------------
__device__ __forceinline__ void lf_core(
    int l, int b, int tid,
    const float* __restrict__ kh, const float* __restrict__ bh,
    const float* __restrict__ w, const float* __restrict__ bias,
    const float* __restrict__ hin, float* __restrict__ hout,
    int layer, int dil,
    float (*xh)[316], float* ks, float (*ws)[36]) {
    const int lane = tid & 63, wv = tid >> 6;
    const int t0 = l * 256;

    const float* hb = hin + (size_t)b * 32 * T;
    for (int idx = tid; idx < 32 * 64; idx += 512) {
        int c = idx >> 6, q = idx & 63;
        float4 v = *(const float4*)(hb + (size_t)c * T + t0 + 4 * q);
        *(float4*)&xh[c][32 + 4 * q] = make_float4(lrelu_f(v.x), lrelu_f(v.y),
                                                   lrelu_f(v.z), lrelu_f(v.w));
    }
    for (int idx = tid; idx < 32 * 60; idx += 512) {
        int c = idx / 60, r = idx - c * 60;
        int jj = (r < 32) ? r : (256 + r);
        int t = t0 + jj - 32;
        xh[c][jj] = (t >= 0 && t < T) ? lrelu_f(hb[(size_t)c * T + t]) : 0.f;
    }
    {
        const float4* kp = (const float4*)(kh + ((size_t)b * LL + l) * KCL);
        float4* kd = (float4*)ks;
        for (int idx = tid; idx < KCL / 4; idx += 512) kd[idx] = kp[idx];
    }
    for (int idx = tid; idx < 3072; idx += 512) {
        int oc = idx / 96, ck = idx - oc * 96;
        ws[ck][oc] = w[oc * 96 + ck];
    }
    __syncthreads();

    // Phase B (R0): wave owns oc4 = wv*4; col = lane + si*64, col<258.
    const int oc4 = wv * 4;
    float yv[5][4];
    {
        float a[5][4];
#pragma unroll
        for (int oi = 0; oi < 4; ++oi) {
            float bv = bias[oc4 + oi];
#pragma unroll
            for (int si = 0; si < 5; ++si) a[si][oi] = bv;
        }
        for (int c = 0; c < 32; ++c) {
#pragma unroll
            for (int k = 0; k < 3; ++k) {
                float4 wq = *(const float4*)&ws[c * 3 + k][oc4];
                float xv[5];
#pragma unroll
                for (int si = 0; si < 5; ++si) {
                    int col = lane + si * 64;
                    int colc = (col < 258) ? col : 257;
                    xv[si] = xh[c][colc + 31 + (k - 1) * dil];
                }
#pragma unroll
                for (int si = 0; si < 5; ++si) {
                    a[si][0] += xv[si] * wq.x;
                    a[si][1] += xv[si] * wq.y;
                    a[si][2] += xv[si] * wq.z;
                    a[si][3] += xv[si] * wq.w;
                }
            }
        }
#pragma unroll
        for (int si = 0; si < 5; ++si) {
            int t = t0 - 1 + lane + si * 64;
            bool tval = (t >= 0 && t < T);
#pragma unroll
            for (int oi = 0; oi < 4; ++oi)
                yv[si][oi] = tval ? lrelu_f(a[si][oi]) : 0.f;
        }
    }
    __syncthreads();

    // Phase C
#pragma unroll
    for (int si = 0; si < 5; ++si) {
        int col = lane + si * 64;
        if (col < 258) {
#pragma unroll
            for (int oi = 0; oi < 4; ++oi) xh[oc4 + oi][col + 31] = yv[si][oi];
        }
    }
    __syncthreads();

    // Phase D (R7 form): wave owns a-chans oc4..+3 and g-chans 32+oc4..+3, all 256 cols.
    float acc_a[4][4], acc_g[4][4];   // [oi][si]
#pragma unroll
    for (int oi = 0; oi < 4; ++oi) {
        float ba = bh[((size_t)b * 256 + layer * 64 + oc4 + oi) * LL + l];
        float bg = bh[((size_t)b * 256 + layer * 64 + 32 + oc4 + oi) * LL + l];
#pragma unroll
        for (int si = 0; si < 4; ++si) { acc_a[oi][si] = ba; acc_g[oi][si] = bg; }
    }

    for (int c = 0; c < 32; ++c) {
#pragma unroll
        for (int k = 0; k < 3; ++k) {
            const float* kr = ks + (c * 3 + k) * 64;
            float4 wa = *(const float4*)(kr + oc4);
            float4 wg = *(const float4*)(kr + 32 + oc4);
            float xv[4];
#pragma unroll
            for (int si = 0; si < 4; ++si)
                xv[si] = xh[c][lane + si * 64 + k + 31];
#pragma unroll
            for (int si = 0; si < 4; ++si) {
                acc_a[0][si] += wa.x * xv[si];
                acc_a[1][si] += wa.y * xv[si];
                acc_a[2][si] += wa.z * xv[si];
                acc_a[3][si] += wa.w * xv[si];
                acc_g[0][si] += wg.x * xv[si];
                acc_g[1][si] += wg.y * xv[si];
                acc_g[2][si] += wg.z * xv[si];
                acc_g[3][si] += wg.w * xv[si];
            }
        }
    }

    // Phase E (R7 form)
#pragma unroll
    for (int oi = 0; oi < 4; ++oi) {
        const float* hip = hin + ((size_t)b * 32 + oc4 + oi) * T + t0;
        float* hop = hout + ((size_t)b * 32 + oc4 + oi) * T + t0;
#pragma unroll
        for (int si = 0; si < 4; ++si) {
            int s = lane + si * 64;
            float a = acc_a[oi][si], g = acc_g[oi][si];
            float sg = 1.f / (1.f + __expf(-a));
            float th = tanhf(g);
            hop[s] = sg * th + hip[s];
        }
    }
}

// ---------------- fused: LF(layer) blocks + KH(layer+1) blocks in one dispatch ----------------
union FusedLDS {
    struct { float xh[32][316]; float ks[KCL]; float ws[96][36]; } lf;  // 77 KB
    struct { float xs[32][264]; float ws[96][36]; } kh;                 // 47.6 KB
};

__global__ void __launch_bounds__(512, 2) fused(
    const float* __restrict__ kp_h, const float* __restrict__ kw,
    const float* __restrict__ kb, const float* __restrict__ bias_w,
    const float* __restrict__ bias_b,
    const float* __restrict__ kh_rd, float* __restrict__ kh_wr,
    float* __restrict__ bh,
    const float* __restrict__ lvcw, const float* __restrict__ lvcb,
    const float* __restrict__ hin, float* __restrict__ hout,
    int lf_layer, int dil, int kh_on) {
    __shared__ FusedLDS u;
    const int g = blockIdx.x;
    const int tid = threadIdx.x;
    if (kh_on) {
        const int r = g % 7, q7 = g / 7;
        if (r < 3) {
            const int ukh = q7 * 3 + r;          // 0..767
            const int bx = ukh % 192, b = ukh / 192;
            khead_core(bx, b, tid, kp_h, kw, kb, bias_w, bias_b,
                       kh_wr, bh, lf_layer + 1, u.kh.xs, u.kh.ws);
            return;
        }
        const int ulf = q7 * 4 + (r - 3);        // 0..1023
        lf_core(ulf & 255, ulf >> 8, tid, kh_rd, bh, lvcw, lvcb,
                hin, hout, lf_layer, dil, u.lf.xh, u.lf.ks, u.lf.ws);
    } else {
        lf_core(g & 255, g >> 8, tid, kh_rd, bh, lvcw, lvcb,
                hin, hout, lf_layer, dil, u.lf.xh, u.lf.ks, u.lf.ws);
    }
}

extern "C" void kernel_launch(void* const* d_in, const int* in_sizes, int n_in,
                              void* d_out, int out_size, void* d_ws, size_t ws_size,
                              hipStream_t stream) {
    const float* hidden  = (const float*)d_in[0];
    const float* spec    = (const float*)d_in[1];
    const float* convt_w = (const float*)d_in[2];
    const float* convt_b = (const float*)d_in[3];
    const float* kp_in_w = (const float*)d_in[4];
    const float* kp_in_b = (const float*)d_in[5];
    const float* rb_w1   = (const float*)d_in[6];
    const float* rb_b1   = (const float*)d_in[7];
    const float* rb_w2   = (const float*)d_in[8];
    const float* rb_b2   = (const float*)d_in[9];
    const float* kern_w  = (const float*)d_in[10];
    const float* kern_b  = (const float*)d_in[11];
    const float* bias_w  = (const float*)d_in[12];
    const float* bias_b  = (const float*)d_in[13];
    const float* lvc_w   = (const float*)d_in[14];
    const float* lvc_b   = (const float*)d_in[15];

    const size_t NH  = (size_t)NB * 32 * T;     // 8,388,608
    const size_t NKH = (size_t)NB * LL * KCL;   // 6,291,456
    const size_t NBH = (size_t)NB * 256 * LL;   //   262,144
    const size_t NKP = (size_t)NB * 64 * LL;    //    65,536
    const size_t need_pp = (NH + 2 * NKH + NBH + NKP) * sizeof(float);  // ~85.2 MB
    const bool pp = ws_size >= need_pp;

    float* wsp  = (float*)d_ws;
    float* h_ws = wsp;
    float* kh0  = h_ws + NH;
    float* kh1  = pp ? (kh0 + NKH) : kh0;
    float* bh   = (pp ? kh1 : kh0) + NKH;
    float* kp_h = bh + NBH;

    float* h0 = (float*)d_out;
    float* h1 = h_ws;

    // 1) merged convt + trunk (R0)
    phase1<<<dim3(296), 512, 0, stream>>>(hidden, convt_w, convt_b, h0,
                                          spec, kp_in_w, kp_in_b,
                                          rb_w1, rb_b1, rb_w2, rb_b2, kp_h);

    // 2) kern head layer 0 (incl. bias blocks)
    kern_head512<<<dim3(200, NB), 512, 0, stream>>>(
        kp_h, kern_w, kern_b, bias_w, bias_b, kh0, bh, 0);

    static const int dil[4] = {1, 3, 9, 27};
    float* hin = h0;
    float* hout = h1;
    for (int l = 0; l < 4; ++l) {
        const float* rd = (l & 1) ? kh1 : kh0;
        float* wr = (l & 1) ? kh0 : kh1;
        if (pp && l < 3) {
            fused<<<dim3(1792), 512, 0, stream>>>(
                kp_h, kern_w, kern_b, bias_w, bias_b, rd, wr, bh,
                lvc_w + (size_t)l * 32 * 32 * 3, lvc_b + l * 32,
                hin, hout, l, dil[l], 1);
        } else {
            fused<<<dim3(1024), 512, 0, stream>>>(
                kp_h, kern_w, kern_b, bias_w, bias_b, rd, (float*)rd, bh,
                lvc_w + (size_t)l * 32 * 32 * 3, lvc_b + l * 32,
                hin, hout, l, dil[l], 0);
            if (!pp && l < 3)
                kern_head512<<<dim3(192, NB), 512, 0, stream>>>(
                    kp_h, kern_w, kern_b, bias_w, bias_b, kh0, bh, l + 1);
        }
        float* tmp = hin; hin = hout; hout = tmp;
    }
    // after 4 swaps the final output landed in h0 = d_out
}

// Round 10
// 667.532 us; speedup vs baseline: 1.1263x; 1.1263x over previous
//
#include <hip/hip_runtime.h>
#include <math.h>

#define NB 4
#define T 65536
#define TIN 8192
#define LL 256
#define KCL 6144   // per-layer kernel channels = 32*64*3

__device__ __forceinline__ float lrelu_f(float v) { return v >= 0.f ? v : 0.2f * v; }

// ---------------- phase1: convt (264 blocks) + trunk (32 blocks) merged (R0, measured 112us) ----------------
union Phase1LDS {
    struct { float xs[32][264]; float wm[64][128]; } cvt;            // 65.8 KB
    struct { float hs[64][56]; float xsp[20][56]; float wt[192][68]; } trk; // 71.0 KB
};

__global__ void __launch_bounds__(512) phase1(
    const float* __restrict__ x, const float* __restrict__ cw,
    const float* __restrict__ cbias, float* __restrict__ hout,
    const float* __restrict__ spec,
    const float* __restrict__ kp_in_w, const float* __restrict__ kp_in_b,
    const float* __restrict__ rb_w1, const float* __restrict__ rb_b1,
    const float* __restrict__ rb_w2, const float* __restrict__ rb_b2,
    float* __restrict__ kp_h) {
    __shared__ Phase1LDS u;
    const int bid = blockIdx.x;
    const int tid = threadIdx.x;
    const int lane = tid & 63, wv = tid >> 6;

    if (bid < 264) {
        // ================= convt role =================
        const int bx = bid % 33;
        const int rr = bid / 33;
        const int mtp = rr & 1;
        const int b = rr >> 1;
        const int s0base = bx * 256;
        float (*xs)[264] = u.cvt.xs;
        float (*wm)[128] = u.cvt.wm;

        const float* xb = x + (size_t)b * 32 * TIN;
        for (int idx = tid; idx < 32 * 64; idx += 512) {
            int c = idx >> 6, q = idx & 63;
            int p = s0base + q * 4;
            float4 v = (p + 3 < TIN) ? *(const float4*)(xb + c * TIN + p)
                                     : make_float4(0.f, 0.f, 0.f, 0.f);
            *(float4*)&xs[c][4 + 4 * q] = v;
        }
        if (tid < 32) {
            int p = s0base - 1;
            xs[tid][3] = (p >= 0) ? xb[tid * TIN + p] : 0.f;
        }
        for (int idx = tid; idx < 8192; idx += 512) {
            int i = idx >> 7, mm = idx & 127;
            int oo = mtp * 16 + (mm >> 3), k0 = mm & 7;
            wm[i][mm] = (i < 32) ? cw[i * 512 + oo * 16 + k0]
                                 : cw[(i - 32) * 512 + oo * 16 + k0 + 8];
        }
        __syncthreads();

        float acc[2][8][4];   // [ol][k0][si]
#pragma unroll
        for (int ol = 0; ol < 2; ++ol) {
            float bo = cbias[mtp * 16 + wv * 2 + ol];
#pragma unroll
            for (int k0 = 0; k0 < 8; ++k0)
#pragma unroll
                for (int si = 0; si < 4; ++si) acc[ol][k0][si] = bo;
        }

        for (int c = 0; c < 32; ++c) {
            float xm1[4], x0[4];
#pragma unroll
            for (int si = 0; si < 4; ++si) {
                xm1[si] = xs[c][lane + si * 64 + 3];
                x0[si]  = xs[c][lane + si * 64 + 4];
            }
            float w0[16], w1[16];
#pragma unroll
            for (int q = 0; q < 4; ++q) {
                *(float4*)&w0[q * 4] = *(const float4*)&wm[c][wv * 16 + q * 4];
                *(float4*)&w1[q * 4] = *(const float4*)&wm[32 + c][wv * 16 + q * 4];
            }
#pragma unroll
            for (int ol = 0; ol < 2; ++ol)
#pragma unroll
                for (int k0 = 0; k0 < 8; ++k0)
#pragma unroll
                    for (int si = 0; si < 4; ++si)
                        acc[ol][k0][si] += x0[si] * w0[ol * 8 + k0] + xm1[si] * w1[ol * 8 + k0];
        }

#pragma unroll
        for (int ol = 0; ol < 2; ++ol) {
            float* ob = hout + ((size_t)b * 32 + mtp * 16 + wv * 2 + ol) * T;
#pragma unroll
            for (int si = 0; si < 4; ++si) {
                int tb = (s0base + lane + si * 64) * 8 - 4;
                if (tb >= 0 && tb < T)
                    *(float4*)(ob + tb) = make_float4(acc[ol][0][si], acc[ol][1][si],
                                                      acc[ol][2][si], acc[ol][3][si]);
                if (tb + 4 >= 0 && tb + 4 < T)
                    *(float4*)(ob + tb + 4) = make_float4(acc[ol][4][si], acc[ol][5][si],
                                                          acc[ol][6][si], acc[ol][7][si]);
            }
        }
        return;
    }

    // ================= trunk role =================
    const int tb = bid - 264;
    const int lq = tb & 7, b = tb >> 3;
    const int j = lane;
    const int oc0 = wv * 8;
    const int l0 = lq * 32;
    const int labs = l0 - 9 + j;
    const bool lvalid = (labs >= 0 && labs < 256);

    float (*hs)[56] = u.trk.hs;
    float (*xsp)[56] = u.trk.xsp;
    float (*wt)[68] = u.trk.wt;

    float pw[24];
    float px[3];

    auto pf_kpin = [&](int cc) {
#pragma unroll
        for (int t = 0; t < 13; ++t) {
            int idx = t * 512 + tid;
            pw[t] = 0.f;
            if (idx < 6400) pw[t] = kp_in_w[(size_t)(idx / 100) * 500 + cc * 100 + (idx % 100)];
        }
    };
    auto wr_kpin = [&]() {
#pragma unroll
        for (int t = 0; t < 13; ++t) {
            int idx = t * 512 + tid;
            if (idx < 6400) wt[idx % 100][idx / 100] = pw[t];
        }
    };
    auto pf_xsp = [&](int cc) {
#pragma unroll
        for (int t = 0; t < 3; ++t) {
            int idx = t * 512 + tid;
            px[t] = 0.f;
            if (idx < 1120) {
                int c = idx / 56, jj = idx - c * 56;
                int l = l0 - 9 + jj;
                if (l >= 0 && l < 256)
                    px[t] = spec[((size_t)b * 100 + cc * 20 + c) * LL + l];
            }
        }
    };
    auto wr_xsp = [&]() {
#pragma unroll
        for (int t = 0; t < 3; ++t) {
            int idx = t * 512 + tid;
            if (idx < 1120) xsp[idx / 56][idx % 56] = px[t];
        }
    };
    auto pf_w192 = [&](const float* src) {
#pragma unroll
        for (int t = 0; t < 24; ++t) pw[t] = src[t * 512 + tid];
    };
    auto wr_w192 = [&]() {
#pragma unroll
        for (int t = 0; t < 24; ++t) {
            int idx = t * 512 + tid;
            wt[idx % 192][idx / 192] = pw[t];
        }
    };
    auto conv64 = [&](int jlo, int jhi, const float* bptr, float* a) {
#pragma unroll
        for (int oi = 0; oi < 8; ++oi) a[oi] = bptr[oc0 + oi];
        if (j >= jlo && j < jhi) {
            for (int c = 0; c < 64; ++c) {
                float x0 = hs[c][j - 1], x1 = hs[c][j], x2 = hs[c][j + 1];
#pragma unroll
                for (int k = 0; k < 3; ++k) {
                    float xk = (k == 0) ? x0 : (k == 1) ? x1 : x2;
                    float w8[8];
                    *(float4*)&w8[0] = *(const float4*)&wt[c * 3 + k][oc0];
                    *(float4*)&w8[4] = *(const float4*)&wt[c * 3 + k][oc0 + 4];
#pragma unroll
                    for (int oi = 0; oi < 8; ++oi) a[oi] += xk * w8[oi];
                }
            }
        }
    };

    // ---- kp_in: 5 cc pages ----
    pf_kpin(0); pf_xsp(0);
    wr_kpin(); wr_xsp();
    __syncthreads();

    float acc[8];
#pragma unroll
    for (int oi = 0; oi < 8; ++oi) acc[oi] = kp_in_b[oc0 + oi];

    for (int cc = 0; cc < 5; ++cc) {
        if (cc < 4) { pf_kpin(cc + 1); pf_xsp(cc + 1); }
        else        { pf_w192(rb_w1); }
        if (j >= 2 && j < 48) {
            for (int c = 0; c < 20; ++c) {
                float x5[5];
#pragma unroll
                for (int u2 = 0; u2 < 5; ++u2) x5[u2] = xsp[c][j - 2 + u2];
#pragma unroll
                for (int k = 0; k < 5; ++k) {
                    float w8[8];
                    *(float4*)&w8[0] = *(const float4*)&wt[c * 5 + k][oc0];
                    *(float4*)&w8[4] = *(const float4*)&wt[c * 5 + k][oc0 + 4];
#pragma unroll
                    for (int oi = 0; oi < 8; ++oi) acc[oi] += x5[k] * w8[oi];
                }
            }
        }
        if (cc == 4 && j >= 2 && j < 48) {
#pragma unroll
            for (int oi = 0; oi < 8; ++oi) hs[oc0 + oi][j] = lvalid ? acc[oi] : 0.f;
        }
        __syncthreads();
        if (cc < 4) { wr_kpin(); wr_xsp(); }
        else        { wr_w192(); }
        __syncthreads();
    }

    // ---- 3 residual blocks ----
    for (int i = 0; i < 3; ++i) {
        const int jlo1 = 3 + 2 * i, jhi1 = 47 - 2 * i;
        const int jlo2 = jlo1 + 1, jhi2 = jhi1 - 1;
        float r[8];
        if (j >= jlo2 && j < jhi2) {
#pragma unroll
            for (int oi = 0; oi < 8; ++oi) r[oi] = hs[oc0 + oi][j];
        }
        // conv1
        pf_w192(rb_w2 + (size_t)i * 12288);
        float a1[8];
        conv64(jlo1, jhi1, rb_b1 + i * 64, a1);
        __syncthreads();
        if (j >= jlo1 && j < jhi1) {
#pragma unroll
            for (int oi = 0; oi < 8; ++oi) hs[oc0 + oi][j] = lvalid ? lrelu_f(a1[oi]) : 0.f;
        }
        wr_w192();
        __syncthreads();
        // conv2
        if (i < 2) pf_w192(rb_w1 + (size_t)(i + 1) * 12288);
        float a2[8];
        conv64(jlo2, jhi2, rb_b2 + i * 64, a2);
        __syncthreads();
        if (j >= jlo2 && j < jhi2) {
#pragma unroll
            for (int oi = 0; oi < 8; ++oi) hs[oc0 + oi][j] = lvalid ? (lrelu_f(a2[oi]) + r[oi]) : 0.f;
        }
        if (i < 2) wr_w192();
        __syncthreads();
    }

    // ---- write kp_h (central 32 cols) ----
    for (int idx = tid; idx < 64 * 32; idx += 512) {
        int c = idx >> 5, jj = idx & 31;
        kp_h[((size_t)b * 64 + c) * LL + l0 + jj] = hs[c][9 + jj];
    }
}

// ---------------- kern head core: 64-oc kern blocks (bx<96), 32-oc bias blocks (bx>=96) ----------------
// x reads: per-lane b32 (col = lane + si*64) — conflict-free. Same per-output accumulation
// order as all previous passing versions.
__device__ __forceinline__ void khead_core(
    int bx, int b, int tid,
    const float* __restrict__ kp_h, const float* __restrict__ kw,
    const float* __restrict__ kb, const float* __restrict__ bias_w,
    const float* __restrict__ bias_b, float* __restrict__ kh,
    float* __restrict__ bh, int layer,
    float (*xs)[264], float (*ws)[68]) {
    const bool isbias = (bx >= 96);
    const int lane = tid & 63, wv = tid >> 6;   // wv 0..7
    int g = 0, ci = 0, kk = 0, ocb0 = 0;
    const float* wsrc;
    size_t wrow0;
    int wstride, nst;
    if (!isbias) {
        g = bx; ci = g / 3; kk = g - ci * 3;
        wsrc = kw + (size_t)layer * KCL * 192;
        wrow0 = (size_t)(ci * 192 + kk) * 192;   // ((ci*64+0)*3+kk)*192
        wstride = 576;
        nst = 96 * 64;
    } else {
        ocb0 = (bx - 96) * 32;
        wsrc = bias_w;
        wrow0 = (size_t)ocb0 * 192;
        wstride = 192;
        nst = 96 * 32;
    }
    const int oc8 = wv * 8;    // kern: wave owns 8 oc
    const int oc4w = wv * 4;   // bias: wave owns 4 oc

    float acc[8][4];
#pragma unroll
    for (int oi = 0; oi < 8; ++oi) {
        float bv;
        if (isbias) bv = (oi < 4) ? bias_b[ocb0 + oc4w + oi] : 0.f;
        else        bv = kb[layer * KCL + (ci * 64 + oc8 + oi) * 3 + kk];
#pragma unroll
        for (int si = 0; si < 4; ++si) acc[oi][si] = bv;
    }

    for (int half = 0; half < 2; ++half) {
        const int hc0 = half * 32;
        __syncthreads();
        for (int idx = tid; idx < 32 * 64; idx += 512) {
            int c = idx >> 6, q = idx & 63;
            *(float4*)&xs[c][4 + 4 * q] =
                *(const float4*)(kp_h + ((size_t)b * 64 + hc0 + c) * LL + 4 * q);
        }
        if (tid < 32) { xs[tid][3] = 0.f; xs[tid][260] = 0.f; }
        for (int idx = tid; idx < nst; idx += 512) {
            int ocl = idx / 96, jj = idx - ocl * 96;
            ws[jj][ocl] = wsrc[wrow0 + (size_t)ocl * wstride + hc0 * 3 + jj];
        }
        __syncthreads();
        if (!isbias) {
            for (int c = 0; c < 32; ++c) {
#pragma unroll
                for (int t = 0; t < 3; ++t) {
                    float w8[8];
                    *(float4*)&w8[0] = *(const float4*)&ws[c * 3 + t][oc8];
                    *(float4*)&w8[4] = *(const float4*)&ws[c * 3 + t][oc8 + 4];
                    float xv[4];
#pragma unroll
                    for (int si = 0; si < 4; ++si) xv[si] = xs[c][lane + si * 64 + t + 3];
#pragma unroll
                    for (int oi = 0; oi < 8; ++oi)
#pragma unroll
                        for (int si = 0; si < 4; ++si)
                            acc[oi][si] += w8[oi] * xv[si];
                }
            }
        } else {
            for (int c = 0; c < 32; ++c) {
#pragma unroll
                for (int t = 0; t < 3; ++t) {
                    float4 w4 = *(const float4*)&ws[c * 3 + t][oc4w];
                    float xv[4];
#pragma unroll
                    for (int si = 0; si < 4; ++si) xv[si] = xs[c][lane + si * 64 + t + 3];
#pragma unroll
                    for (int si = 0; si < 4; ++si) {
                        acc[0][si] += w4.x * xv[si];
                        acc[1][si] += w4.y * xv[si];
                        acc[2][si] += w4.z * xv[si];
                        acc[3][si] += w4.w * xv[si];
                    }
                }
            }
        }
    }

    if (!isbias) {
#pragma unroll
        for (int si = 0; si < 4; ++si) {
            int l = lane + si * 64;
            float* op = kh + ((size_t)b * LL + l) * KCL + g * 64 + oc8;
            *(float4*)(op)     = make_float4(acc[0][si], acc[1][si], acc[2][si], acc[3][si]);
            *(float4*)(op + 4) = make_float4(acc[4][si], acc[5][si], acc[6][si], acc[7][si]);
        }
    } else {
#pragma unroll
        for (int oi = 0; oi < 4; ++oi) {
            float* op = bh + ((size_t)b * 256 + ocb0 + oc4w + oi) * LL;
#pragma unroll
            for (int si = 0; si < 4; ++si)
                op[lane + si * 64] = acc[oi][si];
        }
    }
}

__global__ void __launch_bounds__(512, 2) kern_head512(
    const float* __restrict__ kp_h, const float* __restrict__ kw,
    const float* __restrict__ kb, const float* __restrict__ bias_w,
    const float* __restrict__ bias_b, float* __restrict__ kh,
    float* __restrict__ bh, int layer) {
    __shared__ float xs[32][264];
    __shared__ float ws[96][68];
    khead_core(blockIdx.x, blockIdx.y, threadIdx.x, kp_h, kw, kb, bias_w, bias_b,
               kh, bh, layer, xs, ws);
}

// ---------------- layer_fused core: Phases A/B/C = R0; Phase D/E = R7 form ----------------
__device__ __forceinline__ void lf_core(
    int l, int b, int tid,
    const float* __restrict__ kh, const float* __restrict__ bh,
    const float* __restrict__ w, const float* __restrict__ bias,
    const float* __restrict__ hin, float* __restrict__ hout,
    int layer, int dil,
    float (*xh)[316], float* ks, float (*ws)[36]) {
    const int lane = tid & 63, wv = tid >> 6;
    const int t0 = l * 256;

    const float* hb = hin + (size_t)b * 32 * T;
    for (int idx = tid; idx < 32 * 64; idx += 512) {
        int c = idx >> 6, q = idx & 63;
        float4 v = *(const float4*)(hb + (size_t)c * T + t0 + 4 * q);
        *(float4*)&xh[c][32 + 4 * q] = make_float4(lrelu_f(v.x), lrelu_f(v.y),
                                                   lrelu_f(v.z), lrelu_f(v.w));
    }
    for (int idx = tid; idx < 32 * 60; idx += 512) {
        int c = idx / 60, r = idx - c * 60;
        int jj = (r < 32) ? r : (256 + r);
        int t = t0 + jj - 32;
        xh[c][jj] = (t >= 0 && t < T) ? lrelu_f(hb[(size_t)c * T + t]) : 0.f;
    }
    {
        const float4* kp = (const float4*)(kh + ((size_t)b * LL + l) * KCL);
        float4* kd = (float4*)ks;
        for (int idx = tid; idx < KCL / 4; idx += 512) kd[idx] = kp[idx];
    }
    for (int idx = tid; idx < 3072; idx += 512) {
        int oc = idx / 96, ck = idx - oc * 96;
        ws[ck][oc] = w[oc * 96 + ck];
    }
    __syncthreads();

    // Phase B (R0): wave owns oc4 = wv*4; col = lane + si*64, col<258.
    const int oc4 = wv * 4;
    float yv[5][4];
    {
        float a[5][4];
#pragma unroll
        for (int oi = 0; oi < 4; ++oi) {
            float bv = bias[oc4 + oi];
#pragma unroll
            for (int si = 0; si < 5; ++si) a[si][oi] = bv;
        }
        for (int c = 0; c < 32; ++c) {
#pragma unroll
            for (int k = 0; k < 3; ++k) {
                float4 wq = *(const float4*)&ws[c * 3 + k][oc4];
                float xv[5];
#pragma unroll
                for (int si = 0; si < 5; ++si) {
                    int col = lane + si * 64;
                    int colc = (col < 258) ? col : 257;
                    xv[si] = xh[c][colc + 31 + (k - 1) * dil];
                }
#pragma unroll
                for (int si = 0; si < 5; ++si) {
                    a[si][0] += xv[si] * wq.x;
                    a[si][1] += xv[si] * wq.y;
                    a[si][2] += xv[si] * wq.z;
                    a[si][3] += xv[si] * wq.w;
                }
            }
        }
#pragma unroll
        for (int si = 0; si < 5; ++si) {
            int t = t0 - 1 + lane + si * 64;
            bool tval = (t >= 0 && t < T);
#pragma unroll
            for (int oi = 0; oi < 4; ++oi)
                yv[si][oi] = tval ? lrelu_f(a[si][oi]) : 0.f;
        }
    }
    __syncthreads();

    // Phase C
#pragma unroll
    for (int si = 0; si < 5; ++si) {
        int col = lane + si * 64;
        if (col < 258) {
#pragma unroll
            for (int oi = 0; oi < 4; ++oi) xh[oc4 + oi][col + 31] = yv[si][oi];
        }
    }
    __syncthreads();

    // Phase D (R7 form): wave owns a-chans oc4..+3 and g-chans 32+oc4..+3, all 256 cols.
    float acc_a[4][4], acc_g[4][4];   // [oi][si]
#pragma unroll
    for (int oi = 0; oi < 4; ++oi) {
        float ba = bh[((size_t)b * 256 + layer * 64 + oc4 + oi) * LL + l];
        float bg = bh[((size_t)b * 256 + layer * 64 + 32 + oc4 + oi) * LL + l];
#pragma unroll
        for (int si = 0; si < 4; ++si) { acc_a[oi][si] = ba; acc_g[oi][si] = bg; }
    }

    for (int c = 0; c < 32; ++c) {
#pragma unroll
        for (int k = 0; k < 3; ++k) {
            const float* kr = ks + (c * 3 + k) * 64;
            float4 wa = *(const float4*)(kr + oc4);
            float4 wg = *(const float4*)(kr + 32 + oc4);
            float xv[4];
#pragma unroll
            for (int si = 0; si < 4; ++si)
                xv[si] = xh[c][lane + si * 64 + k + 31];
#pragma unroll
            for (int si = 0; si < 4; ++si) {
                acc_a[0][si] += wa.x * xv[si];
                acc_a[1][si] += wa.y * xv[si];
                acc_a[2][si] += wa.z * xv[si];
                acc_a[3][si] += wa.w * xv[si];
                acc_g[0][si] += wg.x * xv[si];
                acc_g[1][si] += wg.y * xv[si];
                acc_g[2][si] += wg.z * xv[si];
                acc_g[3][si] += wg.w * xv[si];
            }
        }
    }

    // Phase E (R7 form)
#pragma unroll
    for (int oi = 0; oi < 4; ++oi) {
        const float* hip = hin + ((size_t)b * 32 + oc4 + oi) * T + t0;
        float* hop = hout + ((size_t)b * 32 + oc4 + oi) * T + t0;
#pragma unroll
        for (int si = 0; si < 4; ++si) {
            int s = lane + si * 64;
            float a = acc_a[oi][si], g = acc_g[oi][si];
            float sg = 1.f / (1.f + __expf(-a));
            float th = tanhf(g);
            hop[s] = sg * th + hip[s];
        }
    }
}

// ---------------- fused: LF(layer) blocks + KH(layer+1) blocks in one dispatch ----------------
// kh_on=1: grid = 1408 = 11*128; role by bid%11 (3 KH : 8 LF), bijective.
// kh_on=0: grid = 1024, all LF.
union FusedLDS {
    struct { float xh[32][316]; float ks[KCL]; float ws[96][36]; } lf;  // 78.8 KB
    struct { float xs[32][264]; float ws[96][68]; } kh;                 // 59.9 KB
};

__global__ void __launch_bounds__(512, 2) fused(
    const float* __restrict__ kp_h, const float* __restrict__ kw,
    const float* __restrict__ kb, const float* __restrict__ bias_w,
    const float* __restrict__ bias_b,
    const float* __restrict__ kh_rd, float* __restrict__ kh_wr,
    float* __restrict__ bh,
    const float* __restrict__ lvcw, const float* __restrict__ lvcb,
    const float* __restrict__ hin, float* __restrict__ hout,
    int lf_layer, int dil, int kh_on) {
    __shared__ FusedLDS u;
    const int g = blockIdx.x;
    const int tid = threadIdx.x;
    if (kh_on) {
        const int r = g % 11, q11 = g / 11;
        if (r < 3) {
            const int ukh = q11 * 3 + r;         // 0..383
            const int bx = ukh % 96, b = ukh / 96;
            khead_core(bx, b, tid, kp_h, kw, kb, bias_w, bias_b,
                       kh_wr, bh, lf_layer + 1, u.kh.xs, u.kh.ws);
            return;
        }
        const int ulf = q11 * 8 + (r - 3);       // 0..1023
        lf_core(ulf & 255, ulf >> 8, tid, kh_rd, bh, lvcw, lvcb,
                hin, hout, lf_layer, dil, u.lf.xh, u.lf.ks, u.lf.ws);
    } else {
        lf_core(g & 255, g >> 8, tid, kh_rd, bh, lvcw, lvcb,
                hin, hout, lf_layer, dil, u.lf.xh, u.lf.ks, u.lf.ws);
    }
}

extern "C" void kernel_launch(void* const* d_in, const int* in_sizes, int n_in,
                              void* d_out, int out_size, void* d_ws, size_t ws_size,
                              hipStream_t stream) {
    const float* hidden  = (const float*)d_in[0];
    const float* spec    = (const float*)d_in[1];
    const float* convt_w = (const float*)d_in[2];
    const float* convt_b = (const float*)d_in[3];
    const float* kp_in_w = (const float*)d_in[4];
    const float* kp_in_b = (const float*)d_in[5];
    const float* rb_w1   = (const float*)d_in[6];
    const float* rb_b1   = (const float*)d_in[7];
    const float* rb_w2   = (const float*)d_in[8];
    const float* rb_b2   = (const float*)d_in[9];
    const float* kern_w  = (const float*)d_in[10];
    const float* kern_b  = (const float*)d_in[11];
    const float* bias_w  = (const float*)d_in[12];
    const float* bias_b  = (const float*)d_in[13];
    const float* lvc_w   = (const float*)d_in[14];
    const float* lvc_b   = (const float*)d_in[15];

    const size_t NH  = (size_t)NB * 32 * T;     // 8,388,608
    const size_t NKH = (size_t)NB * LL * KCL;   // 6,291,456
    const size_t NBH = (size_t)NB * 256 * LL;   //   262,144
    const size_t NKP = (size_t)NB * 64 * LL;    //    65,536
    const size_t need_pp = (NH + 2 * NKH + NBH + NKP) * sizeof(float);  // ~85.2 MB
    const bool pp = ws_size >= need_pp;

    float* wsp  = (float*)d_ws;
    float* h_ws = wsp;
    float* kh0  = h_ws + NH;
    float* kh1  = pp ? (kh0 + NKH) : kh0;
    float* bh   = (pp ? kh1 : kh0) + NKH;
    float* kp_h = bh + NBH;

    float* h0 = (float*)d_out;
    float* h1 = h_ws;

    // 1) merged convt + trunk (R0)
    phase1<<<dim3(296), 512, 0, stream>>>(hidden, convt_w, convt_b, h0,
                                          spec, kp_in_w, kp_in_b,
                                          rb_w1, rb_b1, rb_w2, rb_b2, kp_h);

    // 2) kern head layer 0 (96 kern blocks + 8 bias blocks)
    kern_head512<<<dim3(104, NB), 512, 0, stream>>>(
        kp_h, kern_w, kern_b, bias_w, bias_b, kh0, bh, 0);

    static const int dil[4] = {1, 3, 9, 27};
    float* hin = h0;
    float* hout = h1;
    for (int l = 0; l < 4; ++l) {
        const float* rd = (l & 1) ? kh1 : kh0;
        float* wr = (l & 1) ? kh0 : kh1;
        if (pp && l < 3) {
            fused<<<dim3(1408), 512, 0, stream>>>(
                kp_h, kern_w, kern_b, bias_w, bias_b, rd, wr, bh,
                lvc_w + (size_t)l * 32 * 32 * 3, lvc_b + l * 32,
                hin, hout, l, dil[l], 1);
        } else {
            fused<<<dim3(1024), 512, 0, stream>>>(
                kp_h, kern_w, kern_b, bias_w, bias_b, rd, (float*)rd, bh,
                lvc_w + (size_t)l * 32 * 32 * 3, lvc_b + l * 32,
                hin, hout, l, dil[l], 0);
            if (!pp && l < 3)
                kern_head512<<<dim3(96, NB), 512, 0, stream>>>(
                    kp_h, kern_w, kern_b, bias_w, bias_b, kh0, bh, l + 1);
        }
        float* tmp = hin; hin = hout; hout = tmp;
    }
    // after 4 swaps the final output landed in h0 = d_out
}